// Round 5
// baseline (512.012 us; speedup 1.0000x reference)
//
#include <hip/hip_runtime.h>

// TGCN forward, algebraically reduced (H0 = 0 => R/Wr dead, Z*H = 0):
//   deg[d] = #in-edges of d ; dinv = rsqrt(deg+1)
//   agg[d] = dinv[d] * ( sum_{e: dst=d} x[src]*dinv[src] + x[d]*dinv[d] )
//   Mz = Wz @ Lzw[0:256], cz = bz @ Lzw[0:256] + Lzb   (same for h)
//   Z = sigmoid(agg@Mz + cz), Ht = tanh(agg@Mh + ch)
//   h = relu((1-Z)*Ht) ; out = softmax(h @ Wo + bo)
//
// R1 -> R2: atomic scatter (2700us) -> CSR build + register gather.
// R2 -> R3: node_kernel 8-node tiling (313 -> ~129us).
// R3 -> R4: scatter 16x write amp -> 2-level bucket sort (793 -> 455us).
// R4 -> R5: node_kernel VALUBusy ~100% at 3x FMA floor with VGPR_Count=84:
// 128-float/thread M arrays forced AGPR/scratch shuttling. Now 512 thr/block,
// (gate, channel) split -> 64-float M column fits in VGPRs; agg row read via
// wave-uniform s_load (SGPR operand FMAs, zero ds_read in main loop).

#define SHIFT 8
#define NPB   256          // nodes per bucket (=1<<SHIFT)
#define BMAX  512          // max buckets (n <= 131072 for 17-bit src packing)
#define TILE  8192         // edges per binning block
#define EPT   32           // edges per thread in binning

__global__ __launch_bounds__(256) void bucket_hist_kernel(const int* __restrict__ dsts,
                                                          int* __restrict__ bdeg,
                                                          int E, int B) {
    __shared__ int h[BMAX];
    for (int i = threadIdx.x; i < B; i += 256) h[i] = 0;
    __syncthreads();
    for (int e = blockIdx.x * 256 + threadIdx.x; e < E; e += gridDim.x * 256)
        atomicAdd(&h[((unsigned)dsts[e]) >> SHIFT], 1);
    __syncthreads();
    for (int i = threadIdx.x; i < B; i += 256)
        if (h[i]) atomicAdd(&bdeg[i], h[i]);
}

__global__ __launch_bounds__(512) void bucket_prefix_kernel(const int* __restrict__ bdeg,
                                                            int* __restrict__ bbase,
                                                            int* __restrict__ bcur, int B) {
    __shared__ int sv[BMAX];
    int tid = threadIdx.x;
    int v = (tid < B) ? bdeg[tid] : 0;
    sv[tid] = v;
    __syncthreads();
    for (int off = 1; off < BMAX; off <<= 1) {
        int t = (tid >= off) ? sv[tid - off] : 0;
        __syncthreads();
        sv[tid] += t;
        __syncthreads();
    }
    int excl = sv[tid] - v;
    if (tid < B) { bbase[tid] = excl; bcur[tid] = excl; }
}

// tile of 8192 edges: LDS histogram -> one global cursor atomic per
// (block,bucket) -> packed (dstLocal<<17 | src) written in contiguous runs
__global__ __launch_bounds__(256) void binning_kernel(const int* __restrict__ srcs,
                                                      const int* __restrict__ dsts,
                                                      int* __restrict__ bcur,
                                                      int* __restrict__ staging,
                                                      int E, int B) {
    __shared__ int h[BMAX];
    __shared__ int cur[BMAX];
    int tile0 = blockIdx.x * TILE;
    for (int i = threadIdx.x; i < B; i += 256) h[i] = 0;
    __syncthreads();
#pragma unroll 4
    for (int j = 0; j < EPT; ++j) {
        int e = tile0 + j * 256 + threadIdx.x;
        if (e < E) atomicAdd(&h[((unsigned)dsts[e]) >> SHIFT], 1);
    }
    __syncthreads();
    for (int i = threadIdx.x; i < B; i += 256)
        cur[i] = h[i] ? atomicAdd(&bcur[i], h[i]) : 0;
    __syncthreads();
#pragma unroll 4
    for (int j = 0; j < EPT; ++j) {
        int e = tile0 + j * 256 + threadIdx.x;
        if (e < E) {
            int d = dsts[e], s = srcs[e];
            int b = ((unsigned)d) >> SHIFT;
            int pos = atomicAdd(&cur[b], 1);
            staging[pos] = ((d & (NPB - 1)) << 17) | s;
        }
    }
}

// one block per bucket: per-node LDS histogram + scan -> start/deg/dinv,
// then scatter srcs inside the bucket's private csr window
__global__ __launch_bounds__(256) void finalize_kernel(const int* __restrict__ staging,
                                                       const int* __restrict__ bdeg,
                                                       const int* __restrict__ bbase,
                                                       int* __restrict__ csr,
                                                       int* __restrict__ deg,
                                                       int* __restrict__ start,
                                                       float* __restrict__ dinv, int n) {
    int b = blockIdx.x;
    int base = bbase[b], count = bdeg[b];
    __shared__ int nd[NPB];
    __shared__ int sv[NPB];
    __shared__ int ncur[NPB];
    int tid = threadIdx.x;
    nd[tid] = 0;
    __syncthreads();
    for (int i = tid; i < count; i += 256)
        atomicAdd(&nd[staging[base + i] >> 17], 1);
    __syncthreads();
    int d0 = nd[tid];
    sv[tid] = d0;
    __syncthreads();
    for (int off = 1; off < NPB; off <<= 1) {
        int t = (tid >= off) ? sv[tid - off] : 0;
        __syncthreads();
        sv[tid] += t;
        __syncthreads();
    }
    int excl = sv[tid] - d0;
    ncur[tid] = excl;
    int node = (b << SHIFT) + tid;
    if (node < n) {
        start[node] = base + excl;
        deg[node] = d0;
        dinv[node] = rsqrtf((float)d0 + 1.0f);
    }
    __syncthreads();
    for (int i = tid; i < count; i += 256) {
        int p = staging[base + i];
        int pos = atomicAdd(&ncur[p >> 17], 1);
        csr[base + pos] = p & 0x1FFFF;
    }
}

// one wave per node (4 waves/block). Lane = (edge_group 0..3) x (chan_quad 0..15).
__global__ __launch_bounds__(256) void gather_kernel(const int* __restrict__ csr,
                                                     const int* __restrict__ start,
                                                     const int* __restrict__ deg,
                                                     const float* __restrict__ x,
                                                     const float* __restrict__ dinv,
                                                     float* __restrict__ agg, int n) {
    int wave = threadIdx.x >> 6;
    int lane = threadIdx.x & 63;
    int node = blockIdx.x * 4 + wave;
    if (node >= n) return;
    int eg = lane >> 4;      // edge group 0..3
    int c  = lane & 15;      // float4 channel quad
    int s0 = start[node];
    int d  = deg[node];
    const float4* x4 = (const float4*)x;
    float4 acc = make_float4(0.f, 0.f, 0.f, 0.f);
    for (int base = 0; base < d; base += 4) {
        int e = base + eg;
        if (e < d) {
            int s = csr[s0 + e];
            float ds = dinv[s];
            float4 v = x4[(size_t)s * 16 + c];
            acc.x = fmaf(v.x, ds, acc.x);
            acc.y = fmaf(v.y, ds, acc.y);
            acc.z = fmaf(v.z, ds, acc.z);
            acc.w = fmaf(v.w, ds, acc.w);
        }
    }
    acc.x += __shfl_down(acc.x, 32); acc.y += __shfl_down(acc.y, 32);
    acc.z += __shfl_down(acc.z, 32); acc.w += __shfl_down(acc.w, 32);
    acc.x += __shfl_down(acc.x, 16); acc.y += __shfl_down(acc.y, 16);
    acc.z += __shfl_down(acc.z, 16); acc.w += __shfl_down(acc.w, 16);
    if (eg == 0) {
        float dn = dinv[node];
        float4 xv = x4[(size_t)node * 16 + c];
        float4 o;
        o.x = dn * fmaf(xv.x, dn, acc.x);
        o.y = dn * fmaf(xv.y, dn, acc.y);
        o.z = dn * fmaf(xv.z, dn, acc.z);
        o.w = dn * fmaf(xv.w, dn, acc.w);
        ((float4*)agg)[(size_t)node * 16 + c] = o;
    }
}

// Mz[k][j] = sum_t W[k][t] * L[t][j]   (k<64);  row k==64 computes the bias fold
__global__ __launch_bounds__(256) void build_m_kernel(
    const float* __restrict__ Wz, const float* __restrict__ bz,
    const float* __restrict__ Wh, const float* __restrict__ bh,
    const float* __restrict__ Lzw, const float* __restrict__ Lzb,
    const float* __restrict__ Lhw, const float* __restrict__ Lhb,
    float* __restrict__ Mz, float* __restrict__ cz,
    float* __restrict__ Mh, float* __restrict__ ch) {
    int j = threadIdx.x;
    int k = blockIdx.x;          // 0..64 (64 == bias row)
    int which = blockIdx.y;      // 0=z, 1=h
    const float* W  = which ? Wh  : Wz;
    const float* bv = which ? bh  : bz;
    const float* L  = which ? Lhw : Lzw;   // [512,256]; only rows 0..255 matter (H0=0)
    const float* Lb = which ? Lhb : Lzb;
    float* M  = which ? Mh : Mz;
    float* cv = which ? ch : cz;
    float acc = 0.f;
    if (k < 64) {
        for (int t = 0; t < 256; ++t) acc = fmaf(W[k * 256 + t], L[t * 256 + j], acc);
        M[k * 256 + j] = acc;
    } else {
        for (int t = 0; t < 256; ++t) acc = fmaf(bv[t], L[t * 256 + j], acc);
        cv[j] = acc + Lb[j];
    }
}

#define NB 16   // nodes per block-iteration (node_kernel)

// 512 threads: thread = (gate g = tid>>8, channel j = tid&255). 64-float M
// column in VGPRs. agg row fetched via wave-uniform s_load -> SGPR-operand
// v_fmac. 16-node tile between barriers; head = 32 threads/node.
__global__ __launch_bounds__(512) void node_kernel(
    const float* __restrict__ agg,
    const float* __restrict__ Mz, const float* __restrict__ cz,
    const float* __restrict__ Mh, const float* __restrict__ ch,
    const float* __restrict__ Wo, const float* __restrict__ bo,
    float* __restrict__ out, int n) {
    int tid = threadIdx.x;
    int gate = tid >> 8;        // 0 = z, 1 = h (wave-uniform)
    int j = tid & 255;
    const float* M = gate ? Mh : Mz;
    float m[64];
#pragma unroll
    for (int k = 0; k < 64; ++k) m[k] = M[k * 256 + j];
    float cj = (gate ? ch : cz)[j];
    __shared__ float sZ[NB][256];    // 16 KB
    __shared__ float sHt[NB][256];   // 16 KB
    __shared__ float sWo[4][256];    // 4 KB (planar: 2-way alias max = free)
    if (tid < 256) {
#pragma unroll
        for (int o = 0; o < 4; ++o) sWo[o][tid] = Wo[tid * 4 + o];
    }
    float bo0 = bo[0], bo1 = bo[1], bo2 = bo[2], bo3 = bo[3];
    int ntiles = (n + NB - 1) / NB;
    for (int tile = blockIdx.x; tile < ntiles; tile += gridDim.x) {
        int node0 = tile * NB;
        for (int nb = 0; nb < NB; ++nb) {
            int node = node0 + nb;                       // wave-uniform
            const float* arow = agg + (size_t)node * 64; // -> s_load
            float acc = cj;
#pragma unroll
            for (int k = 0; k < 64; ++k) acc = fmaf(arow[k], m[k], acc);
            if (gate == 0) {
                sZ[nb][j] = 1.0f / (1.0f + __expf(-acc));          // sigmoid
            } else {
                sHt[nb][j] = 1.0f - 2.0f / (1.0f + __expf(2.0f * acc)); // tanh
            }
        }
        __syncthreads();
        {   // head: 32 threads per node, 8 channels each
            int nb = tid >> 5, g = tid & 31;
            float l0 = 0.f, l1 = 0.f, l2 = 0.f, l3 = 0.f;
#pragma unroll
            for (int i = 0; i < 8; ++i) {
                int c = g + 32 * i;
                float z = sZ[nb][c];
                float ht = sHt[nb][c];
                float hv = fmaxf((1.0f - z) * ht, 0.0f);
                l0 = fmaf(hv, sWo[0][c], l0);
                l1 = fmaf(hv, sWo[1][c], l1);
                l2 = fmaf(hv, sWo[2][c], l2);
                l3 = fmaf(hv, sWo[3][c], l3);
            }
#pragma unroll
            for (int off = 16; off > 0; off >>= 1) {
                l0 += __shfl_down(l0, off, 32);
                l1 += __shfl_down(l1, off, 32);
                l2 += __shfl_down(l2, off, 32);
                l3 += __shfl_down(l3, off, 32);
            }
            int node = node0 + nb;
            if (g == 0 && node < n) {
                float v0 = l0 + bo0, v1 = l1 + bo1, v2 = l2 + bo2, v3 = l3 + bo3;
                float mx = fmaxf(fmaxf(v0, v1), fmaxf(v2, v3));
                float e0 = __expf(v0 - mx), e1 = __expf(v1 - mx);
                float e2 = __expf(v2 - mx), e3 = __expf(v3 - mx);
                float inv = 1.0f / (e0 + e1 + e2 + e3);
                float4 o;
                o.x = e0 * inv; o.y = e1 * inv; o.z = e2 * inv; o.w = e3 * inv;
                ((float4*)out)[node] = o;
            }
        }
        __syncthreads();
    }
}

extern "C" void kernel_launch(void* const* d_in, const int* in_sizes, int n_in,
                              void* d_out, int out_size, void* d_ws, size_t ws_size,
                              hipStream_t stream) {
    const float* x   = (const float*)d_in[0];
    const int*  eidx = (const int*)d_in[1];
    const float* Wz  = (const float*)d_in[2];
    const float* bz  = (const float*)d_in[3];
    // d_in[4]=Wr, d_in[5]=br : dead (H0 = 0)
    const float* Wh  = (const float*)d_in[6];
    const float* bh  = (const float*)d_in[7];
    const float* Lzw = (const float*)d_in[8];
    const float* Lzb = (const float*)d_in[9];
    // d_in[10]=Lrw, d_in[11]=Lrb : dead
    const float* Lhw = (const float*)d_in[12];
    const float* Lhb = (const float*)d_in[13];
    const float* Wo  = (const float*)d_in[14];
    const float* bo  = (const float*)d_in[15];
    float* out = (float*)d_out;

    int n = in_sizes[0] / 64;
    int E = in_sizes[1] / 2;
    const int* srcs = eidx;
    const int* dsts = eidx + E;
    int B = (n + NPB - 1) >> SHIFT;

    size_t na = ((size_t)n + 3) & ~(size_t)3;
    char* ws = (char*)d_ws;
    int*   deg   = (int*)ws;    ws += na * 4;
    int*   start = (int*)ws;    ws += na * 4;
    float* dinv  = (float*)ws;  ws += na * 4;
    int*   bdeg  = (int*)ws;    ws += BMAX * 4;
    int*   bbase = (int*)ws;    ws += BMAX * 4;
    int*   bcur  = (int*)ws;    ws += BMAX * 4;
    int*   csr   = (int*)ws;    ws += (size_t)E * 4;
    float* agg   = (float*)ws;  ws += (size_t)n * 64 * 4;
    int*   staging = (int*)agg;   // aliases agg: staging dead before gather writes
    float* Mz    = (float*)ws;  ws += 64 * 256 * 4;
    float* Mh    = (float*)ws;  ws += 64 * 256 * 4;
    float* cz    = (float*)ws;  ws += 256 * 4;
    float* ch    = (float*)ws;  ws += 256 * 4;

    hipMemsetAsync(bdeg, 0, BMAX * sizeof(int), stream);

    bucket_hist_kernel<<<1024, 256, 0, stream>>>(dsts, bdeg, E, B);
    bucket_prefix_kernel<<<1, BMAX, 0, stream>>>(bdeg, bbase, bcur, B);
    binning_kernel<<<(E + TILE - 1) / TILE, 256, 0, stream>>>(srcs, dsts, bcur,
                                                              staging, E, B);
    finalize_kernel<<<B, 256, 0, stream>>>(staging, bdeg, bbase, csr, deg, start,
                                           dinv, n);
    build_m_kernel<<<dim3(65, 2), 256, 0, stream>>>(Wz, bz, Wh, bh, Lzw, Lzb, Lhw,
                                                    Lhb, Mz, cz, Mh, ch);
    gather_kernel<<<(n + 3) / 4, 256, 0, stream>>>(csr, start, deg, x, dinv, agg, n);
    node_kernel<<<1024, 512, 0, stream>>>(agg, Mz, cz, Mh, ch, Wo, bo, out, n);
}